// Round 7
// baseline (510.538 us; speedup 1.0000x reference)
//
#include <hip/hip_runtime.h>
#include <hip/hip_cooperative_groups.h>
#include <hip/hip_bf16.h>

#define NN 50000
#define NE 600000
#define BAG 16
#define EMB 128
#define HID 128
#define NC 10
#define NG 512
#define PAD_IDX 1
#define VOCAB 10000
#define SLOTS 64                  // fixed-width CSR row; P(deg>64 | lam=12) ~ 1e-30
#define TPAIRS (VOCAB * EMB / 2)  // 640k bf16 pairs in the table
#define WPAIRS (4 * HID * EMB / 2)
#define CONVB ((TPAIRS + WPAIRS + 255) / 256)  // 2688 conversion units
#define NCH1 293                   // ceil(600000/2048) edge chunks (bucket units)
#define RANGES 125                 // dst ranges; NN = 125 * 400 exact
#define RNODES 400                 // nodes per range
#define CSRB (RANGES * 2)          // 250 csr units, 200 nodes each
#define EMVB (NN / 16)             // 3125 embed units (16 nodes each, exact)
#define NTILES ((NN + 127) / 128)  // 391 sage/pool tiles
#define ASTR 40                    // LDS tile row stride (shorts): kills 8-way conflict

typedef __attribute__((ext_vector_type(8))) short v8s;
typedef __attribute__((ext_vector_type(4))) float v4f;

__device__ __forceinline__ float bflo(unsigned u) { return __uint_as_float(u << 16); }
__device__ __forceinline__ float bfhi(unsigned u) { return __uint_as_float(u & 0xffff0000u); }
__device__ __forceinline__ unsigned short f2bf(float f) {
    unsigned u = __float_as_uint(f);
    return (unsigned short)((u + 0x7fffu + ((u >> 16) & 1u)) >> 16);
}
__device__ __forceinline__ void acc8(float* a, v8s v) {
    unsigned* u = (unsigned*)&v;
#pragma unroll
    for (int j = 0; j < 4; j++) {
        a[2 * j] += bflo(u[j]);
        a[2 * j + 1] += bfhi(u[j]);
    }
}

struct MegaArgs {
    const int* src;
    const int* dst;
    unsigned* queue;
    int* qcntG;
    const float* emb_table;
    unsigned short* table_bf;
    const float* w1l;
    const float* w1r;
    const float* w2l;
    const float* w2r;
    unsigned short* wbf;
    float* gsum;
    float* gcnt;
    unsigned short* x0;
    unsigned short* x1;
    unsigned short* aggrb;
    const int* tokens;
    int* cnt;
    unsigned short* slots;
    const int* batch;
    const float* b1;
    const float* b2;
    const float* w_out;
    const float* b_out;
    float* out;
};

// ================= phase unit bodies (shared by mega + fallback) =================

// ---- edge bucketing: chunk u -> 125 dst-range LDS queues -> fixed global segs ----
__device__ __forceinline__ void bucket_unit(int u, const MegaArgs& A, int* qcL,
                                            unsigned* qbL) {
    int tid = threadIdx.x;
    for (int i = tid; i < RANGES; i += 256) qcL[i] = 0;
    __syncthreads();
    int e0 = u * 2048 + tid * 8;
    if (e0 < NE) {  // NE % 8 == 0 -> full octet valid
        int4 s0 = *((const int4*)(A.src + e0));
        int4 s1 = *((const int4*)(A.src + e0) + 1);
        int4 d0 = *((const int4*)(A.dst + e0));
        int4 d1 = *((const int4*)(A.dst + e0) + 1);
        int ss[8] = {s0.x, s0.y, s0.z, s0.w, s1.x, s1.y, s1.z, s1.w};
        int dd[8] = {d0.x, d0.y, d0.z, d0.w, d1.x, d1.y, d1.z, d1.w};
#pragma unroll
        for (int j = 0; j < 8; j++) {
            int q = dd[j] / RNODES;
            unsigned pk = ((unsigned)(dd[j] - q * RNODES) << 16) | (unsigned)ss[j];
            int pos = atomicAdd(&qcL[q], 1);
            if (pos < 64) qbL[q * 64 + pos] = pk;  // cap 64 = +11.8 sigma (mean 16.4)
        }
    }
    __syncthreads();
    if (tid < RANGES) {
        int n = qcL[tid];
        if (n > 64) n = 64;
        A.qcntG[tid * NCH1 + u] = n;
        unsigned* qp = A.queue + ((size_t)tid * NCH1 + u) * 64;
        for (int k = 0; k < n; k++) qp[k] = qbL[tid * 64 + k];
    }
    __syncthreads();  // qbL reads done before any LDS reuse
}

// ---- fp32->bf16 conversion / workspace zeroing, element index i ----
__device__ __forceinline__ void conv_unit(int i, const MegaArgs& A) {
    if (i < NG * HID) A.gsum[i] = 0.f;
    if (i < NG) A.gcnt[i] = 0.f;
    if (i < 64) {  // zero sentinel rows (128 bf16 each, as 64 u32)
        ((unsigned*)(A.x0 + (size_t)NN * EMB))[i] = 0;
        ((unsigned*)(A.x1 + (size_t)NN * HID))[i] = 0;  // no clash: table rows < VOCAB
    }
    if (i < TPAIRS) {
        float2 v = *(const float2*)(A.emb_table + (size_t)i * 2);
        unsigned lo = f2bf(v.x), hi = f2bf(v.y);
        *(unsigned*)(A.table_bf + (size_t)i * 2) = lo | (hi << 16);
    } else if (i < TPAIRS + WPAIRS) {
        int j = i - TPAIRS;
        int k = j * 2;      // element in concatenated [w1l|w1r|w2l|w2r]
        int arr = k >> 14;  // 16384 elements per matrix
        int o = k & 16383;
        const float* w = (arr == 0) ? A.w1l : (arr == 1) ? A.w1r : (arr == 2) ? A.w2l
                                                                              : A.w2r;
        float2 v = *(const float2*)(w + o);
        unsigned lo = f2bf(v.x), hi = f2bf(v.y);
        *(unsigned*)(A.wbf + k) = lo | (hi << 16);
    }
}

// ---- CSR build for half-range u (200 nodes) entirely in LDS, coalesced flush ----
__device__ __forceinline__ void csr_unit(int u, const MegaArgs& A, int* cntL,
                                         unsigned short* slotsL) {
    int tid = threadIdx.x;
    int r = u >> 1, half = u & 1;
    for (int i = tid; i < 200; i += 256) cntL[i] = 0;
    __syncthreads();
    int dlo = half * 200;
    for (int c = tid; c < NCH1; c += 256) {
        int n = A.qcntG[r * NCH1 + c];
        const unsigned* qp = A.queue + ((size_t)r * NCH1 + c) * 64;
        for (int k = 0; k < n; k++) {
            unsigned v = qp[k];
            int d2 = (int)(v >> 16) - dlo;
            if ((unsigned)d2 < 200u) {
                int p = atomicAdd(&cntL[d2], 1);
                if (p < SLOTS) slotsL[d2 * SLOTS + p] = (unsigned short)(v & 0xffffu);
            }
        }
    }
    __syncthreads();
    for (int i = tid; i < 200; i += 256) {  // pad rows to multiple of 8
        int d = cntL[i];
        if (d > SLOTS) d = SLOTS;
        int d8 = (d + 7) & ~7;
        if (d8 > SLOTS) d8 = SLOTS;
        for (int p = d; p < d8; p++) slotsL[i * SLOTS + p] = (unsigned short)NN;
    }
    __syncthreads();
    int nb = r * RNODES + half * 200;
    uint4* gs = (uint4*)(A.slots + (size_t)nb * SLOTS);
    const uint4* ls = (const uint4*)slotsL;
    for (int i = tid; i < 200 * SLOTS / 8; i += 256) gs[i] = ls[i];  // 1600 uint4
    for (int i = tid; i < 200; i += 256) A.cnt[nb + i] = cntL[i];
    __syncthreads();  // slotsL reads done before any LDS reuse
}

// ---- embedding-bag mean for 16-node unit u: 16-lane group/node, 16 gathers ----
__device__ __forceinline__ void embed_unit(int u, const MegaArgs& A) {
    int tid = threadIdx.x;
    int sl = tid & 15;
    int node = u * 16 + (tid >> 4);  // exact: NN = 3125*16
    const int* tp = A.tokens + node * BAG;
    int tk[16];
    *(int4*)(tk) = *(const int4*)(tp);
    *(int4*)(tk + 4) = *(const int4*)(tp + 4);
    *(int4*)(tk + 8) = *(const int4*)(tp + 8);
    *(int4*)(tk + 12) = *(const int4*)(tp + 12);
    int c = 0;
#pragma unroll
    for (int t = 0; t < BAG; t++) c += (tk[t] != PAD_IDX);
    float a[8];
#pragma unroll
    for (int j = 0; j < 8; j++) a[j] = 0.f;
    v8s v[16];
#pragma unroll
    for (int t = 0; t < 16; t++)
        v[t] = *(const v8s*)(A.table_bf + (size_t)tk[t] * EMB + sl * 8);
#pragma unroll
    for (int t = 0; t < 16; t++) acc8(a, v[t]);
    float inv = 1.0f / (float)(c > 0 ? c : 1);
    uint4 o;
    o.x = f2bf(a[0] * inv) | ((unsigned)f2bf(a[1] * inv) << 16);
    o.y = f2bf(a[2] * inv) | ((unsigned)f2bf(a[3] * inv) << 16);
    o.z = f2bf(a[4] * inv) | ((unsigned)f2bf(a[5] * inv) << 16);
    o.w = f2bf(a[6] * inv) | ((unsigned)f2bf(a[7] * inv) << 16);
    *(uint4*)(A.x0 + (size_t)node * EMB + sl * 8) = o;
}

// ---- neighbor mean for 8-node unit u (2 nodes/wave, padded-to-8 slot rows) ----
__device__ __forceinline__ void aggr_unit(int u, const unsigned short* __restrict__ x,
                                          const int* __restrict__ cnt,
                                          const unsigned short* __restrict__ slots,
                                          unsigned short* __restrict__ aggr) {
    int wv = threadIdx.x >> 6;
    int lane = threadIdx.x & 63;
    int g = lane >> 4, sl = lane & 15;
    int n0 = (u * 4 + wv) * 2;  // exact: NN = 6250*8
    int n1 = n0 + 1;
    int deg0 = cnt[n0], deg1 = cnt[n1];
    int m0 = deg0 > SLOTS ? SLOTS : deg0;
    int m1 = deg1 > SLOTS ? SLOTS : deg1;
    int m80 = (m0 + 7) & ~7;
    int m81 = (m1 + 7) & ~7;
    int idx0 = slots[(size_t)n0 * SLOTS + lane];
    int idx1 = slots[(size_t)n1 * SLOTS + lane];
    float a0[8], a1[8];
#pragma unroll
    for (int j = 0; j < 8; j++) {
        a0[j] = 0.f;
        a1[j] = 0.f;
    }
    int mm = m80 > m81 ? m80 : m81;
#pragma unroll 2
    for (int i = 0; i < mm; i += 8) {
        bool c0 = (i < m80), c1 = (i < m81);  // wave-uniform branches
        v8s w0, w1, w2, w3;
        if (c0) {
            int t00 = __shfl(idx0, i + g, 64);
            int t01 = __shfl(idx0, i + 4 + g, 64);
            w0 = *(const v8s*)(x + (size_t)t00 * HID + sl * 8);
            w1 = *(const v8s*)(x + (size_t)t01 * HID + sl * 8);
        }
        if (c1) {
            int t10 = __shfl(idx1, i + g, 64);
            int t11 = __shfl(idx1, i + 4 + g, 64);
            w2 = *(const v8s*)(x + (size_t)t10 * HID + sl * 8);
            w3 = *(const v8s*)(x + (size_t)t11 * HID + sl * 8);
        }
        if (c0) {
            acc8(a0, w0);
            acc8(a0, w1);
        }
        if (c1) {
            acc8(a1, w2);
            acc8(a1, w3);
        }
    }
#pragma unroll
    for (int j = 0; j < 8; j++) {
        a0[j] += __shfl_xor(a0[j], 16, 64);
        a0[j] += __shfl_xor(a0[j], 32, 64);
        a1[j] += __shfl_xor(a1[j], 16, 64);
        a1[j] += __shfl_xor(a1[j], 32, 64);
    }
    if (g == 0) {
        float inv = 1.0f / (float)(deg0 > 0 ? deg0 : 1);
        uint4 o;
        o.x = f2bf(a0[0] * inv) | ((unsigned)f2bf(a0[1] * inv) << 16);
        o.y = f2bf(a0[2] * inv) | ((unsigned)f2bf(a0[3] * inv) << 16);
        o.z = f2bf(a0[4] * inv) | ((unsigned)f2bf(a0[5] * inv) << 16);
        o.w = f2bf(a0[6] * inv) | ((unsigned)f2bf(a0[7] * inv) << 16);
        *(uint4*)(aggr + (size_t)n0 * HID + sl * 8) = o;
    } else if (g == 1) {
        float inv = 1.0f / (float)(deg1 > 0 ? deg1 : 1);
        uint4 o;
        o.x = f2bf(a1[0] * inv) | ((unsigned)f2bf(a1[1] * inv) << 16);
        o.y = f2bf(a1[2] * inv) | ((unsigned)f2bf(a1[3] * inv) << 16);
        o.z = f2bf(a1[4] * inv) | ((unsigned)f2bf(a1[5] * inv) << 16);
        o.w = f2bf(a1[6] * inv) | ((unsigned)f2bf(a1[7] * inv) << 16);
        *(uint4*)(aggr + (size_t)n1 * HID + sl * 8) = o;
    }
}

// ---- shared MFMA K-loop for a 128-row tile (software-pipelined, ASTR stride) ----
__device__ __forceinline__ void sage_kloop(int row0, const unsigned short* __restrict__ xa,
                                           const unsigned short* __restrict__ xr,
                                           const unsigned short* __restrict__ wl,
                                           const unsigned short* __restrict__ wr,
                                           unsigned short* As, unsigned short* Bs,
                                           v4f acc[2][8]) {
    int tid = threadIdx.x;
    int wave = tid >> 6, lane = tid & 63;
    int q = lane >> 4, l16 = lane & 15;
    int r0 = tid >> 2, sg = tid & 3;  // it=0: rows 0..63
    int r1 = (tid + 256) >> 2;        // it=1: rows 64..127 (same sg)
    int gr0 = row0 + r0;
    if (gr0 > NN - 1) gr0 = NN - 1;
    int gr1 = row0 + r1;
    if (gr1 > NN - 1) gr1 = NN - 1;
    v8s ra0 = *(const v8s*)(xa + (size_t)gr0 * HID + sg * 8);
    v8s ra1 = *(const v8s*)(xa + (size_t)gr1 * HID + sg * 8);
    v8s rb0 = *(const v8s*)(wl + (size_t)r0 * HID + sg * 8);
    v8s rb1 = *(const v8s*)(wl + (size_t)r1 * HID + sg * 8);
    for (int kc = 0; kc < 8; kc++) {
        __syncthreads();  // prior kc's (or prior tile's) LDS reads complete
        *(v8s*)(As + r0 * ASTR + sg * 8) = ra0;
        *(v8s*)(As + r1 * ASTR + sg * 8) = ra1;
        *(v8s*)(Bs + r0 * ASTR + sg * 8) = rb0;
        *(v8s*)(Bs + r1 * ASTR + sg * 8) = rb1;
        __syncthreads();
        if (kc < 7) {  // prefetch next chunk; latency overlaps MFMA below
            int kn = kc + 1;
            const unsigned short* Ag = (kn < 4) ? xa : xr;
            const unsigned short* Bg = (kn < 4) ? wl : wr;
            int koff = (kn & 3) * 32;
            ra0 = *(const v8s*)(Ag + (size_t)gr0 * HID + koff + sg * 8);
            ra1 = *(const v8s*)(Ag + (size_t)gr1 * HID + koff + sg * 8);
            rb0 = *(const v8s*)(Bg + (size_t)r0 * HID + koff + sg * 8);
            rb1 = *(const v8s*)(Bg + (size_t)r1 * HID + koff + sg * 8);
        }
        v8s a0 = *(const v8s*)(As + (wave * 32 + l16) * ASTR + q * 8);
        v8s a1 = *(const v8s*)(As + (wave * 32 + 16 + l16) * ASTR + q * 8);
#pragma unroll
        for (int nt = 0; nt < 8; nt++) {
            v8s b = *(const v8s*)(Bs + (nt * 16 + l16) * ASTR + q * 8);
            acc[0][nt] = __builtin_amdgcn_mfma_f32_16x16x32_bf16(a0, b, acc[0][nt], 0, 0, 0);
            acc[1][nt] = __builtin_amdgcn_mfma_f32_16x16x32_bf16(a1, b, acc[1][nt], 0, 0, 0);
        }
    }
    __syncthreads();  // LDS reads done before caller reuses the tile
}

// ---- SAGE layer 1 tile u: relu(aggr@w1l^T + b1 + x0@w1r^T) -> x1 ----
__device__ __forceinline__ void sage1_unit(int u, const MegaArgs& A, unsigned short* As,
                                           unsigned short* Bs) {
    int row0 = u * 128;
    v4f acc[2][8];
#pragma unroll
    for (int m = 0; m < 2; m++)
#pragma unroll
        for (int n = 0; n < 8; n++) acc[m][n] = (v4f){0.f, 0.f, 0.f, 0.f};
    sage_kloop(row0, A.aggrb, A.x0, A.wbf, A.wbf + 16384, As, Bs, acc);
    int tid = threadIdx.x;
    int wave = tid >> 6, lane = tid & 63;
    int q = lane >> 4, l16 = lane & 15;
#pragma unroll
    for (int nt = 0; nt < 8; nt++) {
        int col = nt * 16 + l16;
        float bv = A.b1[col];
#pragma unroll
        for (int mt = 0; mt < 2; mt++) {
#pragma unroll
            for (int r = 0; r < 4; r++) {
                int row = row0 + wave * 32 + mt * 16 + q * 4 + r;
                if (row < NN) {
                    float v = acc[mt][nt][r] + bv;
                    v = v > 0.f ? v : 0.f;
                    A.x1[(size_t)row * HID + col] = f2bf(v);
                }
            }
        }
    }
}

// ---- SAGE layer 2 tile u fused with run-length global mean pool (smem = 32KB) ----
__device__ __forceinline__ void sagepool_unit(int u, const MegaArgs& A,
                                              unsigned short* smem) {
    unsigned short* As = smem;
    unsigned short* Bs = smem + 128 * ASTR;
    int row0 = u * 128;
    v4f acc[2][8];
#pragma unroll
    for (int m = 0; m < 2; m++)
#pragma unroll
        for (int n = 0; n < 8; n++) acc[m][n] = (v4f){0.f, 0.f, 0.f, 0.f};
    sage_kloop(row0, A.aggrb, A.x1, A.wbf + 32768, A.wbf + 49152, As, Bs, acc);
    // kloop ends with __syncthreads(); As/Bs dead -> overlay x2 tile
    int tid = threadIdx.x;
    int wave = tid >> 6, lane = tid & 63;
    int q = lane >> 4, l16 = lane & 15;
#pragma unroll
    for (int nt = 0; nt < 8; nt++) {
        int col = nt * 16 + l16;
        float bv = A.b2[col];
#pragma unroll
        for (int mt = 0; mt < 2; mt++) {
#pragma unroll
            for (int r = 0; r < 4; r++) {
                int rl = wave * 32 + mt * 16 + q * 4 + r;  // local row 0..127
                float v = acc[mt][nt][r] + bv;
                v = v > 0.f ? v : 0.f;
                smem[rl * 128 + col] = f2bf(v);
            }
        }
    }
    __syncthreads();
    if (tid < 128) {
        int col = tid;
        int end = NN - row0;
        if (end > 128) end = 128;
        int cur = A.batch[row0];
        float acc_p = 0.f;
        int c = 0;
        for (int i = 0; i < end; i++) {
            int b = A.batch[row0 + i];  // uniform across block
            if (b != cur) {
                atomicAdd(&A.gsum[cur * HID + col], acc_p);
                if (col == 0) atomicAdd(&A.gcnt[cur], (float)c);
                acc_p = 0.f;
                c = 0;
                cur = b;
            }
            acc_p += __uint_as_float(((unsigned)smem[i * 128 + col]) << 16);
            c++;
        }
        atomicAdd(&A.gsum[cur * HID + col], acc_p);
        if (col == 0) atomicAdd(&A.gcnt[cur], (float)c);
    }
    __syncthreads();  // smem reads done before next tile's kloop writes
}

// ---- final classifier, 2 graphs per unit ----
__device__ __forceinline__ void final_unit(int u, const MegaArgs& A, float* mean) {
    int tid = threadIdx.x;
    __syncthreads();  // mean[] safe to overwrite (prior unit / prior phase)
    int g = u * 2 + (tid >> 7);
    int t = tid & 127;
    mean[tid] = A.gsum[g * HID + t] / fmaxf(A.gcnt[g], 1.0f);
    __syncthreads();
    if (t < NC) {
        float s = A.b_out[t];
        const float* wo = A.w_out + t * HID;
        const float* mn = mean + (tid >> 7) * 128;
#pragma unroll 16
        for (int d = 0; d < HID; d++) s += mn[d] * wo[d];
        A.out[g * NC + t] = s;
    }
}

// ================= single cooperative kernel: all 7 phases =================
// Grid size comes from the runtime occupancy query (round-6 lesson: hardcoded 768
// failed validation -> launch error -> zero output). All loops stride by gridDim.x.
__global__ __launch_bounds__(256, 3) void k_mega(MegaArgs A) {
    cooperative_groups::grid_group gg = cooperative_groups::this_grid();
    __shared__ __align__(16) char SM[33024];
    int bid = blockIdx.x, gsz = gridDim.x;
    for (int u = bid; u < NCH1 + CONVB; u += gsz) {
        if (u < NCH1)
            bucket_unit(u, A, (int*)SM, (unsigned*)(SM + 512));
        else
            conv_unit((u - NCH1) * 256 + threadIdx.x, A);
    }
    gg.sync();
    for (int u = bid; u < CSRB + EMVB; u += gsz) {
        if (u < CSRB)
            csr_unit(u, A, (int*)SM, (unsigned short*)(SM + 1024));
        else
            embed_unit(u - CSRB, A);
    }
    gg.sync();
    for (int u = bid; u < NN / 8; u += gsz) aggr_unit(u, A.x0, A.cnt, A.slots, A.aggrb);
    gg.sync();
    for (int u = bid; u < NTILES; u += gsz)
        sage1_unit(u, A, (unsigned short*)SM, (unsigned short*)SM + 128 * ASTR);
    gg.sync();
    for (int u = bid; u < NN / 8; u += gsz) aggr_unit(u, A.x1, A.cnt, A.slots, A.aggrb);
    gg.sync();
    for (int u = bid; u < NTILES; u += gsz) sagepool_unit(u, A, (unsigned short*)SM);
    gg.sync();
    for (int u = bid; u < NG / 2; u += gsz) final_unit(u, A, (float*)SM);
}

// ================= fallback: round-5 7-kernel sequence (identical bodies) =======
__global__ __launch_bounds__(256) void k_conv(MegaArgs A) {
    __shared__ int qcL[RANGES];
    __shared__ unsigned qbL[RANGES * 64];
    int b = blockIdx.x;
    if (b < NCH1)
        bucket_unit(b, A, qcL, qbL);
    else
        conv_unit((b - NCH1) * 256 + threadIdx.x, A);
}

__global__ __launch_bounds__(256) void k_scatem(MegaArgs A) {
    __shared__ int cntL[200];
    __shared__ __align__(16) unsigned short slotsL[200 * SLOTS];
    int b = blockIdx.x;
    if (b < CSRB)
        csr_unit(b, A, cntL, slotsL);
    else
        embed_unit(b - CSRB, A);
}

__global__ __launch_bounds__(256) void k_aggr(const unsigned short* __restrict__ x,
                                              const int* __restrict__ cnt,
                                              const unsigned short* __restrict__ slots,
                                              unsigned short* __restrict__ aggr) {
    aggr_unit(blockIdx.x, x, cnt, slots, aggr);
}

__global__ __launch_bounds__(256) void k_sage(MegaArgs A) {
    __shared__ unsigned short As[128 * ASTR];
    __shared__ unsigned short Bs[128 * ASTR];
    sage1_unit(blockIdx.x, A, As, Bs);
}

__global__ __launch_bounds__(256) void k_sagepool(MegaArgs A) {
    __shared__ __align__(16) unsigned short smem[128 * 128];
    sagepool_unit(blockIdx.x, A, smem);
}

__global__ __launch_bounds__(256) void k_final(MegaArgs A) {
    __shared__ float mean[256];
    final_unit(blockIdx.x, A, mean);
}

extern "C" void kernel_launch(void* const* d_in, const int* in_sizes, int n_in,
                              void* d_out, int out_size, void* d_ws, size_t ws_size,
                              hipStream_t stream) {
    char* ws = (char*)d_ws;
    size_t off = 0;
    auto alloc = [&](size_t bytes) {
        void* p = ws + off;
        off += (bytes + 255) & ~(size_t)255;
        return p;
    };
    int* cnt = (int*)alloc(NN * 4);
    unsigned short* slots = (unsigned short*)alloc((size_t)NN * SLOTS * 2);  // 6.4 MB
    unsigned short* wbf = (unsigned short*)alloc(4 * HID * EMB * 2);
    float* gsum = (float*)alloc(NG * HID * 4);
    float* gcnt = (float*)alloc(NG * 4);
    unsigned short* x0 = (unsigned short*)alloc((size_t)(NN + 1) * EMB * 2);  // +zero row
    unsigned short* x1 = (unsigned short*)alloc((size_t)(NN + 1) * HID * 2);  // +zero row
    unsigned short* aggrb = (unsigned short*)alloc((size_t)NN * HID * 2);
    unsigned* queue = (unsigned*)alloc((size_t)RANGES * NCH1 * 64 * 4);  // 9.4 MB
    int* qcntG = (int*)alloc((size_t)RANGES * NCH1 * 4);                 // 146 KB

    MegaArgs h;
    h.src = (const int*)d_in[1];
    h.dst = (const int*)d_in[1] + NE;
    h.queue = queue;
    h.qcntG = qcntG;
    h.emb_table = (const float*)d_in[3];
    h.table_bf = x1;  // x1 rows < VOCAB dead until sage1 writes them; reuse
    h.w1l = (const float*)d_in[4];
    h.w1r = (const float*)d_in[6];
    h.w2l = (const float*)d_in[7];
    h.w2r = (const float*)d_in[9];
    h.wbf = wbf;
    h.gsum = gsum;
    h.gcnt = gcnt;
    h.x0 = x0;
    h.x1 = x1;
    h.aggrb = aggrb;
    h.tokens = (const int*)d_in[0];
    h.cnt = cnt;
    h.slots = slots;
    h.batch = (const int*)d_in[2];
    h.b1 = (const float*)d_in[5];
    h.b2 = (const float*)d_in[8];
    h.w_out = (const float*)d_in[10];
    h.b_out = (const float*)d_in[11];
    h.out = (float*)d_out;

    // Cooperative path: occupancy-derived grid (host query only; capture-safe).
    bool done = false;
    int nb = 0;
    hipError_t qe =
        hipOccupancyMaxActiveBlocksPerMultiprocessor(&nb, (const void*)k_mega, 256, 0);
    if (qe == hipSuccess && nb > 0) {
        int grid = nb * 256;  // 256 CUs on MI355X; loops are grid-stride, any size OK
        if (grid > 2048) grid = 2048;
        void* args[] = {&h};
        if (hipLaunchCooperativeKernel((const void*)k_mega, dim3(grid), dim3(256), args,
                                       0, stream) == hipSuccess)
            done = true;
    }
    if (!done) {  // fallback: known-good multi-launch sequence
        k_conv<<<NCH1 + CONVB, 256, 0, stream>>>(h);
        k_scatem<<<CSRB + EMVB, 256, 0, stream>>>(h);
        k_aggr<<<NN / 8, 256, 0, stream>>>(h.x0, h.cnt, h.slots, h.aggrb);
        k_sage<<<NTILES, 256, 0, stream>>>(h);
        k_aggr<<<NN / 8, 256, 0, stream>>>(h.x1, h.cnt, h.slots, h.aggrb);
        k_sagepool<<<NTILES, 256, 0, stream>>>(h);
        k_final<<<NG / 2, 256, 0, stream>>>(h);
    }
}

// Round 9
// 243.143 us; speedup vs baseline: 2.0997x; 2.0997x over previous
//
#include <hip/hip_runtime.h>
#include <hip/hip_bf16.h>

#define NN 50000
#define NE 600000
#define BAG 16
#define EMB 128
#define HID 128
#define NC 10
#define NG 512
#define PAD_IDX 1
#define VOCAB 10000
#define SLOTS 64                  // fixed-width CSR row; P(deg>64 | lam=12) ~ 1e-30
#define TPAIRS (VOCAB * EMB / 2)  // 640k bf16 pairs in the table
#define WPAIRS (4 * HID * EMB / 2)
#define CONVB ((TPAIRS + WPAIRS + 255) / 256)  // 2688 conversion units
#define NCH1 293                   // ceil(600000/2048) edge chunks (bucket units)
#define RANGES 125                 // dst ranges; NN = 125 * 400 exact
#define RNODES 400                 // nodes per range
#define CSRB (RANGES * 2)          // 250 csr units, 200 nodes each
#define EMVB (NN / 16)             // 3125 embed units (16 nodes each, exact)
#define NTILES ((NN + 127) / 128)  // 391 sage/pool tiles
#define ASTR 40                    // As/Bs row stride (shorts): kills 8-way conflict
#define AXS 136                    // Ax row stride (shorts); 272B = 17x16B -> aligned,
                                   // fragment reads ~2-way on banks (free per m136)

typedef __attribute__((ext_vector_type(8))) short v8s;
typedef __attribute__((ext_vector_type(4))) float v4f;

__device__ __forceinline__ float bflo(unsigned u) { return __uint_as_float(u << 16); }
__device__ __forceinline__ float bfhi(unsigned u) { return __uint_as_float(u & 0xffff0000u); }
__device__ __forceinline__ unsigned short f2bf(float f) {
    unsigned u = __float_as_uint(f);
    return (unsigned short)((u + 0x7fffu + ((u >> 16) & 1u)) >> 16);
}
__device__ __forceinline__ void acc8(float* a, v8s v) {
    unsigned* u = (unsigned*)&v;
#pragma unroll
    for (int j = 0; j < 4; j++) {
        a[2 * j] += bflo(u[j]);
        a[2 * j + 1] += bfhi(u[j]);
    }
}

struct Args {
    const int* src;
    const int* dst;
    unsigned* queue;
    int* qcntG;
    const float* emb_table;
    unsigned short* table_bf;
    const float* w1l;
    const float* w1r;
    const float* w2l;
    const float* w2r;
    unsigned short* wbf;
    float* gsum;
    float* gcnt;
    unsigned short* x0;
    unsigned short* x1;
    const int* tokens;
    int* cnt;
    unsigned short* slots;
    const int* batch;
    const float* b1;
    const float* b2;
    const float* w_out;
    const float* b_out;
    float* out;
};

// ---------- k_conv: edge bucketing (293 blocks) + fp32->bf16 conversion ----------
__global__ __launch_bounds__(256) void k_conv(Args A) {
    __shared__ int qcL[RANGES];
    __shared__ unsigned qbL[RANGES * 64];  // 32.5KB
    int b = blockIdx.x;
    int tid = threadIdx.x;
    if (b < NCH1) {  // bucket chunk b into 125 dst-range LDS queues, burst-flush
        for (int i = tid; i < RANGES; i += 256) qcL[i] = 0;
        __syncthreads();
        int e0 = b * 2048 + tid * 8;
        if (e0 < NE) {  // NE % 8 == 0 -> full octet valid
            int4 s0 = *((const int4*)(A.src + e0));
            int4 s1 = *((const int4*)(A.src + e0) + 1);
            int4 d0 = *((const int4*)(A.dst + e0));
            int4 d1 = *((const int4*)(A.dst + e0) + 1);
            int ss[8] = {s0.x, s0.y, s0.z, s0.w, s1.x, s1.y, s1.z, s1.w};
            int dd[8] = {d0.x, d0.y, d0.z, d0.w, d1.x, d1.y, d1.z, d1.w};
#pragma unroll
            for (int j = 0; j < 8; j++) {
                int q = dd[j] / RNODES;
                unsigned pk = ((unsigned)(dd[j] - q * RNODES) << 16) | (unsigned)ss[j];
                int pos = atomicAdd(&qcL[q], 1);
                if (pos < 64) qbL[q * 64 + pos] = pk;  // cap 64 = +11.8 sigma
            }
        }
        __syncthreads();
        if (tid < RANGES) {
            int n = qcL[tid];
            if (n > 64) n = 64;
            A.qcntG[tid * NCH1 + b] = n;
            unsigned* qp = A.queue + ((size_t)tid * NCH1 + b) * 64;
            for (int k = 0; k < n; k++) qp[k] = qbL[tid * 64 + k];
        }
        return;
    }
    int i = (b - NCH1) * 256 + tid;
    if (i < NG * HID) A.gsum[i] = 0.f;
    if (i < NG) A.gcnt[i] = 0.f;
    if (i < 64) {  // zero sentinel rows NN of x0/x1 (aggr pads gathers with idx NN)
        ((unsigned*)(A.x0 + (size_t)NN * EMB))[i] = 0;
        ((unsigned*)(A.x1 + (size_t)NN * HID))[i] = 0;  // table uses rows < VOCAB only
    }
    if (i < TPAIRS) {
        float2 v = *(const float2*)(A.emb_table + (size_t)i * 2);
        unsigned lo = f2bf(v.x), hi = f2bf(v.y);
        *(unsigned*)(A.table_bf + (size_t)i * 2) = lo | (hi << 16);
    } else if (i < TPAIRS + WPAIRS) {
        int j = i - TPAIRS;
        int k = j * 2;      // element in concatenated [w1l|w1r|w2l|w2r]
        int arr = k >> 14;  // 16384 elements per matrix
        int o = k & 16383;
        const float* w = (arr == 0) ? A.w1l : (arr == 1) ? A.w1r : (arr == 2) ? A.w2l
                                                                              : A.w2r;
        float2 v = *(const float2*)(w + o);
        unsigned lo = f2bf(v.x), hi = f2bf(v.y);
        *(unsigned*)(A.wbf + k) = lo | (hi << 16);
    }
}

// ---------- k_scatem: CSR build (250 blocks) + embedding-bag mean ----------
__global__ __launch_bounds__(256) void k_scatem(Args A) {
    __shared__ int cntL[200];
    __shared__ __align__(16) unsigned short slotsL[200 * SLOTS];  // 25.6KB
    int b = blockIdx.x;
    int tid = threadIdx.x;
    if (b < CSRB) {  // half-range CSR entirely in LDS, coalesced flush
        int r = b >> 1, half = b & 1;
        for (int i = tid; i < 200; i += 256) cntL[i] = 0;
        __syncthreads();
        int dlo = half * 200;
        for (int c = tid; c < NCH1; c += 256) {
            int n = A.qcntG[r * NCH1 + c];
            const unsigned* qp = A.queue + ((size_t)r * NCH1 + c) * 64;
            for (int k = 0; k < n; k++) {
                unsigned v = qp[k];
                int d2 = (int)(v >> 16) - dlo;
                if ((unsigned)d2 < 200u) {
                    int p = atomicAdd(&cntL[d2], 1);
                    if (p < SLOTS) slotsL[d2 * SLOTS + p] = (unsigned short)(v & 0xffffu);
                }
            }
        }
        __syncthreads();
        for (int i = tid; i < 200; i += 256) {  // pad rows to multiple of 8
            int d = cntL[i];
            if (d > SLOTS) d = SLOTS;
            int d8 = (d + 7) & ~7;
            if (d8 > SLOTS) d8 = SLOTS;
            for (int p = d; p < d8; p++) slotsL[i * SLOTS + p] = (unsigned short)NN;
        }
        __syncthreads();
        int nb = r * RNODES + half * 200;
        uint4* gs = (uint4*)(A.slots + (size_t)nb * SLOTS);
        const uint4* ls = (const uint4*)slotsL;
        for (int i = tid; i < 200 * SLOTS / 8; i += 256) gs[i] = ls[i];
        for (int i = tid; i < 200; i += 256) A.cnt[nb + i] = cntL[i];
        return;
    }
    // embed: one 16-lane group per node, 16 gathers in flight; table L2-resident
    int sl = tid & 15;
    int node = (b - CSRB) * 16 + (tid >> 4);  // exact: NN = 3125*16
    const int* tp = A.tokens + node * BAG;
    int tk[16];
    *(int4*)(tk) = *(const int4*)(tp);
    *(int4*)(tk + 4) = *(const int4*)(tp + 4);
    *(int4*)(tk + 8) = *(const int4*)(tp + 8);
    *(int4*)(tk + 12) = *(const int4*)(tp + 12);
    int c = 0;
#pragma unroll
    for (int t = 0; t < BAG; t++) c += (tk[t] != PAD_IDX);
    float a[8];
#pragma unroll
    for (int j = 0; j < 8; j++) a[j] = 0.f;
    v8s v[16];
#pragma unroll
    for (int t = 0; t < 16; t++)
        v[t] = *(const v8s*)(A.table_bf + (size_t)tk[t] * EMB + sl * 8);
#pragma unroll
    for (int t = 0; t < 16; t++) acc8(a, v[t]);
    float inv = 1.0f / (float)(c > 0 ? c : 1);
    uint4 o;
    o.x = f2bf(a[0] * inv) | ((unsigned)f2bf(a[1] * inv) << 16);
    o.y = f2bf(a[2] * inv) | ((unsigned)f2bf(a[3] * inv) << 16);
    o.z = f2bf(a[4] * inv) | ((unsigned)f2bf(a[5] * inv) << 16);
    o.w = f2bf(a[6] * inv) | ((unsigned)f2bf(a[7] * inv) << 16);
    *(uint4*)(A.x0 + (size_t)node * EMB + sl * 8) = o;
}

// ---------- aggregate this tile's 128 rows into LDS Ax (bit-identical to the old
// aggr kernel: same per-node gather order, same f2bf) ----------
__device__ __forceinline__ void aggr_to_lds(int row0, const unsigned short* __restrict__ x,
                                            const int* __restrict__ cnt,
                                            const unsigned short* __restrict__ slots,
                                            unsigned short* Ax) {
    int wv = threadIdx.x >> 6;
    int lane = threadIdx.x & 63;
    int g = lane >> 4, sl = lane & 15;
    for (int p = 0; p < 16; p++) {  // 4 waves x 2 nodes/pass x 16 passes = 128 rows
        int lr0 = p * 8 + wv * 2, lr1 = lr0 + 1;
        int n0 = row0 + lr0;
        if (n0 > NN - 1) n0 = NN - 1;
        int n1 = row0 + lr1;
        if (n1 > NN - 1) n1 = NN - 1;
        int deg0 = cnt[n0], deg1 = cnt[n1];
        int m0 = deg0 > SLOTS ? SLOTS : deg0;
        int m1 = deg1 > SLOTS ? SLOTS : deg1;
        int m80 = (m0 + 7) & ~7;
        int m81 = (m1 + 7) & ~7;
        int idx0 = slots[(size_t)n0 * SLOTS + lane];
        int idx1 = slots[(size_t)n1 * SLOTS + lane];
        float a0[8], a1[8];
#pragma unroll
        for (int j = 0; j < 8; j++) {
            a0[j] = 0.f;
            a1[j] = 0.f;
        }
        int mm = m80 > m81 ? m80 : m81;
#pragma unroll 2
        for (int i = 0; i < mm; i += 8) {
            bool c0 = (i < m80), c1 = (i < m81);  // wave-uniform branches
            v8s w0, w1, w2, w3;
            if (c0) {
                int t00 = __shfl(idx0, i + g, 64);
                int t01 = __shfl(idx0, i + 4 + g, 64);
                w0 = *(const v8s*)(x + (size_t)t00 * HID + sl * 8);
                w1 = *(const v8s*)(x + (size_t)t01 * HID + sl * 8);
            }
            if (c1) {
                int t10 = __shfl(idx1, i + g, 64);
                int t11 = __shfl(idx1, i + 4 + g, 64);
                w2 = *(const v8s*)(x + (size_t)t10 * HID + sl * 8);
                w3 = *(const v8s*)(x + (size_t)t11 * HID + sl * 8);
            }
            if (c0) {
                acc8(a0, w0);
                acc8(a0, w1);
            }
            if (c1) {
                acc8(a1, w2);
                acc8(a1, w3);
            }
        }
#pragma unroll
        for (int j = 0; j < 8; j++) {
            a0[j] += __shfl_xor(a0[j], 16, 64);
            a0[j] += __shfl_xor(a0[j], 32, 64);
            a1[j] += __shfl_xor(a1[j], 16, 64);
            a1[j] += __shfl_xor(a1[j], 32, 64);
        }
        if (g == 0) {
            float inv = 1.0f / (float)(deg0 > 0 ? deg0 : 1);
            uint4 o;
            o.x = f2bf(a0[0] * inv) | ((unsigned)f2bf(a0[1] * inv) << 16);
            o.y = f2bf(a0[2] * inv) | ((unsigned)f2bf(a0[3] * inv) << 16);
            o.z = f2bf(a0[4] * inv) | ((unsigned)f2bf(a0[5] * inv) << 16);
            o.w = f2bf(a0[6] * inv) | ((unsigned)f2bf(a0[7] * inv) << 16);
            *(uint4*)(Ax + (size_t)lr0 * AXS + sl * 8) = o;
        } else if (g == 1) {
            float inv = 1.0f / (float)(deg1 > 0 ? deg1 : 1);
            uint4 o;
            o.x = f2bf(a1[0] * inv) | ((unsigned)f2bf(a1[1] * inv) << 16);
            o.y = f2bf(a1[2] * inv) | ((unsigned)f2bf(a1[3] * inv) << 16);
            o.z = f2bf(a1[4] * inv) | ((unsigned)f2bf(a1[5] * inv) << 16);
            o.w = f2bf(a1[6] * inv) | ((unsigned)f2bf(a1[7] * inv) << 16);
            *(uint4*)(Ax + (size_t)lr1 * AXS + sl * 8) = o;
        }
    }
    __syncthreads();  // Ax complete before the K-loop reads it
}

// ---------- MFMA K-loop: A from LDS Ax for kc<4, staged xr for kc>=4 ----------
__device__ __forceinline__ void sage_kloop_f(int row0, const unsigned short* __restrict__ xr,
                                             const unsigned short* __restrict__ wl,
                                             const unsigned short* __restrict__ wr,
                                             const unsigned short* Ax, unsigned short* As,
                                             unsigned short* Bs, v4f acc[2][8]) {
    int tid = threadIdx.x;
    int wave = tid >> 6, lane = tid & 63;
    int q = lane >> 4, l16 = lane & 15;
    int r0 = tid >> 2, sg = tid & 3;  // rows 0..63
    int r1 = r0 + 64;                 // rows 64..127
    int gr0 = row0 + r0;
    if (gr0 > NN - 1) gr0 = NN - 1;
    int gr1 = row0 + r1;
    if (gr1 > NN - 1) gr1 = NN - 1;
    v8s ra0, ra1;
    v8s rb0 = *(const v8s*)(wl + (size_t)r0 * HID + sg * 8);
    v8s rb1 = *(const v8s*)(wl + (size_t)r1 * HID + sg * 8);
    for (int kc = 0; kc < 8; kc++) {
        __syncthreads();  // prior kc's (or prior phase's) LDS reads complete
        *(v8s*)(Bs + r0 * ASTR + sg * 8) = rb0;
        *(v8s*)(Bs + r1 * ASTR + sg * 8) = rb1;
        if (kc >= 4) {
            *(v8s*)(As + r0 * ASTR + sg * 8) = ra0;
            *(v8s*)(As + r1 * ASTR + sg * 8) = ra1;
        }
        __syncthreads();
        if (kc < 7) {  // prefetch next chunk; latency overlaps MFMA below
            int kn = kc + 1;
            const unsigned short* Bg = (kn < 4) ? wl : wr;
            int koff = (kn & 3) * 32;
            rb0 = *(const v8s*)(Bg + (size_t)r0 * HID + koff + sg * 8);
            rb1 = *(const v8s*)(Bg + (size_t)r1 * HID + koff + sg * 8);
            if (kn >= 4) {
                ra0 = *(const v8s*)(xr + (size_t)gr0 * HID + koff + sg * 8);
                ra1 = *(const v8s*)(xr + (size_t)gr1 * HID + koff + sg * 8);
            }
        }
        v8s a0, a1;
        if (kc < 4) {  // A direct from Ax (aggregated rows live in LDS)
            a0 = *(const v8s*)(Ax + (size_t)(wave * 32 + l16) * AXS + kc * 32 + q * 8);
            a1 = *(const v8s*)(Ax + (size_t)(wave * 32 + 16 + l16) * AXS + kc * 32 + q * 8);
        } else {
            a0 = *(const v8s*)(As + (wave * 32 + l16) * ASTR + q * 8);
            a1 = *(const v8s*)(As + (wave * 32 + 16 + l16) * ASTR + q * 8);
        }
#pragma unroll
        for (int nt = 0; nt < 8; nt++) {
            v8s b = *(const v8s*)(Bs + (nt * 16 + l16) * ASTR + q * 8);
            acc[0][nt] = __builtin_amdgcn_mfma_f32_16x16x32_bf16(a0, b, acc[0][nt], 0, 0, 0);
            acc[1][nt] = __builtin_amdgcn_mfma_f32_16x16x32_bf16(a1, b, acc[1][nt], 0, 0, 0);
        }
    }
    __syncthreads();  // LDS reads done before caller reuses the tile
}

// ---------- fused SAGE layer 1: aggr(x0) in-LDS + GEMM -> x1 ----------
// LDS: Ax 34.8KB + As/Bs 20KB = 54.8KB -> 2 blocks/CU (matches VGPR limit anyway)
__global__ __launch_bounds__(256) void k_sage1f(Args A) {
    __shared__ __align__(16) unsigned short SM[AXS * 128 + ASTR * 128 * 2];
    unsigned short* Ax = SM;
    unsigned short* As = SM + AXS * 128;
    unsigned short* Bs = As + ASTR * 128;
    int row0 = blockIdx.x * 128;
    aggr_to_lds(row0, A.x0, A.cnt, A.slots, Ax);
    v4f acc[2][8];
#pragma unroll
    for (int m = 0; m < 2; m++)
#pragma unroll
        for (int n = 0; n < 8; n++) acc[m][n] = (v4f){0.f, 0.f, 0.f, 0.f};
    sage_kloop_f(row0, A.x0, A.wbf, A.wbf + 16384, Ax, As, Bs, acc);
    int tid = threadIdx.x;
    int wave = tid >> 6, lane = tid & 63;
    int q = lane >> 4, l16 = lane & 15;
#pragma unroll
    for (int nt = 0; nt < 8; nt++) {
        int col = nt * 16 + l16;
        float bv = A.b1[col];
#pragma unroll
        for (int mt = 0; mt < 2; mt++) {
#pragma unroll
            for (int r = 0; r < 4; r++) {
                int row = row0 + wave * 32 + mt * 16 + q * 4 + r;
                if (row < NN) {
                    float v = acc[mt][nt][r] + bv;
                    v = v > 0.f ? v : 0.f;
                    A.x1[(size_t)row * HID + col] = f2bf(v);
                }
            }
        }
    }
}

// ---------- fused SAGE layer 2: aggr(x1) in-LDS + GEMM + run-length pool ----------
__global__ __launch_bounds__(256) void k_sage2f(Args A) {
    __shared__ __align__(16) unsigned short SM[AXS * 128 + ASTR * 128 * 2];
    unsigned short* Ax = SM;
    unsigned short* As = SM + AXS * 128;
    unsigned short* Bs = As + ASTR * 128;
    int row0 = blockIdx.x * 128;
    aggr_to_lds(row0, A.x1, A.cnt, A.slots, Ax);
    v4f acc[2][8];
#pragma unroll
    for (int m = 0; m < 2; m++)
#pragma unroll
        for (int n = 0; n < 8; n++) acc[m][n] = (v4f){0.f, 0.f, 0.f, 0.f};
    sage_kloop_f(row0, A.x1, A.wbf + 32768, A.wbf + 49152, Ax, As, Bs, acc);
    // kloop ends with __syncthreads(); Ax dead -> overlay the x2 tile (32KB<=34.8KB)
    unsigned short* smem = Ax;
    int tid = threadIdx.x;
    int wave = tid >> 6, lane = tid & 63;
    int q = lane >> 4, l16 = lane & 15;
#pragma unroll
    for (int nt = 0; nt < 8; nt++) {
        int col = nt * 16 + l16;
        float bv = A.b2[col];
#pragma unroll
        for (int mt = 0; mt < 2; mt++) {
#pragma unroll
            for (int r = 0; r < 4; r++) {
                int rl = wave * 32 + mt * 16 + q * 4 + r;  // local row 0..127
                float v = acc[mt][nt][r] + bv;
                v = v > 0.f ? v : 0.f;
                smem[rl * 128 + col] = f2bf(v);
            }
        }
    }
    __syncthreads();
    if (tid < 128) {  // run-length pool over this tile's sorted rows
        int col = tid;
        int end = NN - row0;
        if (end > 128) end = 128;
        int cur = A.batch[row0];
        float acc_p = 0.f;
        int c = 0;
        for (int i = 0; i < end; i++) {
            int b = A.batch[row0 + i];  // uniform across block
            if (b != cur) {
                atomicAdd(&A.gsum[cur * HID + col], acc_p);
                if (col == 0) atomicAdd(&A.gcnt[cur], (float)c);
                acc_p = 0.f;
                c = 0;
                cur = b;
            }
            acc_p += __uint_as_float(((unsigned)smem[i * 128 + col]) << 16);
            c++;
        }
        atomicAdd(&A.gsum[cur * HID + col], acc_p);
        if (col == 0) atomicAdd(&A.gcnt[cur], (float)c);
    }
}

// ---------- final classifier (2 graphs per block) ----------
__global__ __launch_bounds__(256) void k_final(Args A) {
    __shared__ float mean[256];
    int tid = threadIdx.x;
    int g = blockIdx.x * 2 + (tid >> 7);
    int t = tid & 127;
    mean[tid] = A.gsum[g * HID + t] / fmaxf(A.gcnt[g], 1.0f);
    __syncthreads();
    if (t < NC) {
        float s = A.b_out[t];
        const float* wo = A.w_out + t * HID;
        const float* mn = mean + (tid >> 7) * 128;
#pragma unroll 16
        for (int d = 0; d < HID; d++) s += mn[d] * wo[d];
        A.out[g * NC + t] = s;
    }
}

extern "C" void kernel_launch(void* const* d_in, const int* in_sizes, int n_in,
                              void* d_out, int out_size, void* d_ws, size_t ws_size,
                              hipStream_t stream) {
    char* ws = (char*)d_ws;
    size_t off = 0;
    auto alloc = [&](size_t bytes) {
        void* p = ws + off;
        off += (bytes + 255) & ~(size_t)255;
        return p;
    };
    int* cnt = (int*)alloc(NN * 4);
    unsigned short* slots = (unsigned short*)alloc((size_t)NN * SLOTS * 2);  // 6.4 MB
    unsigned short* wbf = (unsigned short*)alloc(4 * HID * EMB * 2);
    float* gsum = (float*)alloc(NG * HID * 4);
    float* gcnt = (float*)alloc(NG * 4);
    unsigned short* x0 = (unsigned short*)alloc((size_t)(NN + 1) * EMB * 2);  // +zero row
    unsigned short* x1 = (unsigned short*)alloc((size_t)(NN + 1) * HID * 2);  // +zero row
    unsigned* queue = (unsigned*)alloc((size_t)RANGES * NCH1 * 64 * 4);  // 9.4 MB
    int* qcntG = (int*)alloc((size_t)RANGES * NCH1 * 4);                 // 146 KB

    Args h;
    h.src = (const int*)d_in[1];
    h.dst = (const int*)d_in[1] + NE;
    h.queue = queue;
    h.qcntG = qcntG;
    h.emb_table = (const float*)d_in[3];
    h.table_bf = x1;  // x1 rows < VOCAB dead until sage1 writes them; reuse
    h.w1l = (const float*)d_in[4];
    h.w1r = (const float*)d_in[6];
    h.w2l = (const float*)d_in[7];
    h.w2r = (const float*)d_in[9];
    h.wbf = wbf;
    h.gsum = gsum;
    h.gcnt = gcnt;
    h.x0 = x0;
    h.x1 = x1;
    h.tokens = (const int*)d_in[0];
    h.cnt = cnt;
    h.slots = slots;
    h.batch = (const int*)d_in[2];
    h.b1 = (const float*)d_in[5];
    h.b2 = (const float*)d_in[8];
    h.w_out = (const float*)d_in[10];
    h.b_out = (const float*)d_in[11];
    h.out = (float*)d_out;

    k_conv<<<NCH1 + CONVB, 256, 0, stream>>>(h);
    k_scatem<<<CSRB + EMVB, 256, 0, stream>>>(h);
    k_sage1f<<<NTILES, 256, 0, stream>>>(h);
    k_sage2f<<<NTILES, 256, 0, stream>>>(h);
    k_final<<<NG / 2, 256, 0, stream>>>(h);
}

// Round 10
// 195.444 us; speedup vs baseline: 2.6122x; 1.2441x over previous
//
#include <hip/hip_runtime.h>
#include <hip/hip_bf16.h>

#define NN 50000
#define NE 600000
#define BAG 16
#define EMB 128
#define HID 128
#define NC 10
#define NG 512
#define PAD_IDX 1
#define VOCAB 10000
#define SLOTS 64                  // fixed-width CSR row; P(deg>64 | lam=12) ~ 1e-30
#define TPAIRS (VOCAB * EMB / 2)  // 640k bf16 pairs in the table
#define WPAIRS (4 * HID * EMB / 2)
#define CONVB ((TPAIRS + WPAIRS + 255) / 256)  // 2688 conversion blocks
#define NCH1 293                   // ceil(600000/2048) edge chunks (bucket blocks)
#define RANGES 125                 // dst ranges; NN = 125 * 400 exact
#define RNODES 400                 // nodes per range
#define CSRB (RANGES * 2)          // 250 csr blocks, 200 nodes each
#define EMVB (NN / 16)             // 3125 embed blocks (16 nodes each, exact)
#define NTILES ((NN + 127) / 128)  // 391 sage/pool tiles
#define ASTR 40                    // LDS tile row stride (shorts): breaks 8-way bank conflict

typedef __attribute__((ext_vector_type(8))) short v8s;
typedef __attribute__((ext_vector_type(4))) float v4f;

__device__ __forceinline__ float bflo(unsigned u) { return __uint_as_float(u << 16); }
__device__ __forceinline__ float bfhi(unsigned u) { return __uint_as_float(u & 0xffff0000u); }
__device__ __forceinline__ unsigned short f2bf(float f) {
    unsigned u = __float_as_uint(f);
    return (unsigned short)((u + 0x7fffu + ((u >> 16) & 1u)) >> 16);
}
__device__ __forceinline__ void acc8(float* a, v8s v) {
    unsigned* u = (unsigned*)&v;
#pragma unroll
    for (int j = 0; j < 4; j++) {
        a[2 * j] += bflo(u[j]);
        a[2 * j + 1] += bfhi(u[j]);
    }
}

// ---------- fused: edge bucketing (293 blocks) + fp32->bf16 conversion ----------
// Bucketing is independent of conversion -> same launch, overlapped. Each chunk
// block buckets its 2048 edges into 125 dst-range LDS queues, then flushes each
// queue to a FIXED per-(range,chunk) 64-entry segment (no global atomics at all;
// count goes to qcntG). Conversion blocks stream table+weights to bf16 and zero
// gsum/gcnt + the sentinel rows NN of x0/x1 (aggr pads gathers with index NN).
__global__ __launch_bounds__(256) void k_conv(const int* __restrict__ src,
                                              const int* __restrict__ dst,
                                              unsigned* __restrict__ queue,
                                              int* __restrict__ qcntG,
                                              const float* __restrict__ t,
                                              unsigned short* __restrict__ tb,
                                              const float* __restrict__ w1l,
                                              const float* __restrict__ w1r,
                                              const float* __restrict__ w2l,
                                              const float* __restrict__ w2r,
                                              unsigned short* __restrict__ wbf,
                                              float* __restrict__ gsum,
                                              float* __restrict__ gcnt,
                                              unsigned short* __restrict__ x0,
                                              unsigned short* __restrict__ x1) {
    __shared__ int qcL[RANGES];
    __shared__ unsigned qbL[RANGES * 64];  // 32.5KB
    int b = blockIdx.x;
    int tid = threadIdx.x;
    if (b < NCH1) {  // ---- bucket chunk b ----
        for (int i = tid; i < RANGES; i += 256) qcL[i] = 0;
        __syncthreads();
        int e0 = b * 2048 + tid * 8;
        if (e0 < NE) {  // NE % 8 == 0 -> full octet valid
            int4 s0 = *((const int4*)(src + e0));
            int4 s1 = *((const int4*)(src + e0) + 1);
            int4 d0 = *((const int4*)(dst + e0));
            int4 d1 = *((const int4*)(dst + e0) + 1);
            int ss[8] = {s0.x, s0.y, s0.z, s0.w, s1.x, s1.y, s1.z, s1.w};
            int dd[8] = {d0.x, d0.y, d0.z, d0.w, d1.x, d1.y, d1.z, d1.w};
#pragma unroll
            for (int j = 0; j < 8; j++) {
                int q = dd[j] / RNODES;
                unsigned pk = ((unsigned)(dd[j] - q * RNODES) << 16) | (unsigned)ss[j];
                int pos = atomicAdd(&qcL[q], 1);
                if (pos < 64) qbL[q * 64 + pos] = pk;  // cap 64 = +11.8 sigma (mean 16.4)
            }
        }
        __syncthreads();
        if (tid < RANGES) {
            int n = qcL[tid];
            if (n > 64) n = 64;
            qcntG[tid * NCH1 + b] = n;
            unsigned* qp = queue + ((size_t)tid * NCH1 + b) * 64;
            for (int k = 0; k < n; k++) qp[k] = qbL[tid * 64 + k];
        }
        return;
    }
    // ---- conversion / zeroing ----
    int i = (b - NCH1) * 256 + tid;
    if (i < NG * HID) gsum[i] = 0.f;
    if (i < NG) gcnt[i] = 0.f;
    if (i < 64) {  // zero sentinel rows (128 bf16 each, as 64 u32)
        ((unsigned*)(x0 + (size_t)NN * EMB))[i] = 0;
        ((unsigned*)(x1 + (size_t)NN * HID))[i] = 0;  // no clash: table uses rows < VOCAB
    }
    if (i < TPAIRS) {
        float2 v = *(const float2*)(t + (size_t)i * 2);
        unsigned lo = f2bf(v.x), hi = f2bf(v.y);
        *(unsigned*)(tb + (size_t)i * 2) = lo | (hi << 16);
    } else if (i < TPAIRS + WPAIRS) {
        int j = i - TPAIRS;
        int k = j * 2;      // element index in concatenated [w1l|w1r|w2l|w2r]
        int arr = k >> 14;  // 16384 elements per matrix
        int o = k & 16383;
        const float* w = (arr == 0) ? w1l : (arr == 1) ? w1r : (arr == 2) ? w2l : w2r;
        float2 v = *(const float2*)(w + o);
        unsigned lo = f2bf(v.x), hi = f2bf(v.y);
        *(unsigned*)(wbf + k) = lo | (hi << 16);
    }
}

// ---------- fused: CSR build (250 blocks) + embedding-bag mean ----------
// CSR block bi owns 200 nodes (half of range bi>>1): streams that range's queue
// segments, builds cnt+slots in 26.4KB LDS, pads rows to a multiple of 8 with
// sentinel NN, flushes coalesced. Embed blocks: one 16-lane group per node, all
// 16 bag gathers in flight; PAD row of the table is exactly zero.
__global__ __launch_bounds__(256) void k_scatem(const int* __restrict__ qcntG,
                                                const unsigned* __restrict__ queue,
                                                int* __restrict__ cnt,
                                                unsigned short* __restrict__ slots,
                                                const int* __restrict__ tokens,
                                                const unsigned short* __restrict__ table,
                                                unsigned short* __restrict__ x0) {
    __shared__ int cntL[200];
    __shared__ __align__(16) unsigned short slotsL[200 * SLOTS];  // 25.6KB
    int b = blockIdx.x;
    int tid = threadIdx.x;
    if (b < CSRB) {  // ---- csr half-range ----
        int r = b >> 1, half = b & 1;
        for (int i = tid; i < 200; i += 256) cntL[i] = 0;
        __syncthreads();
        int dlo = half * 200;
        for (int c = tid; c < NCH1; c += 256) {
            int n = qcntG[r * NCH1 + c];
            const unsigned* qp = queue + ((size_t)r * NCH1 + c) * 64;
            for (int k = 0; k < n; k++) {
                unsigned u = qp[k];
                int d2 = (int)(u >> 16) - dlo;
                if ((unsigned)d2 < 200u) {
                    int p = atomicAdd(&cntL[d2], 1);
                    if (p < SLOTS) slotsL[d2 * SLOTS + p] = (unsigned short)(u & 0xffffu);
                }
            }
        }
        __syncthreads();
        for (int i = tid; i < 200; i += 256) {  // pad rows to multiple of 8
            int d = cntL[i];
            if (d > SLOTS) d = SLOTS;
            int d8 = (d + 7) & ~7;
            if (d8 > SLOTS) d8 = SLOTS;
            for (int p = d; p < d8; p++) slotsL[i * SLOTS + p] = (unsigned short)NN;
        }
        __syncthreads();
        int nb = r * RNODES + half * 200;
        uint4* gs = (uint4*)(slots + (size_t)nb * SLOTS);
        const uint4* ls = (const uint4*)slotsL;
        for (int i = tid; i < 200 * SLOTS / 8; i += 256) gs[i] = ls[i];  // 1600 uint4
        for (int i = tid; i < 200; i += 256) cnt[nb + i] = cntL[i];
        return;
    }
    // ---- embed: one 16-lane group per node, 16 gathers in flight ----
    int sl = tid & 15;
    int node = (b - CSRB) * 16 + (tid >> 4);  // exact: NN = 3125*16
    const int* tp = tokens + node * BAG;
    int tk[16];
    *(int4*)(tk) = *(const int4*)(tp);
    *(int4*)(tk + 4) = *(const int4*)(tp + 4);
    *(int4*)(tk + 8) = *(const int4*)(tp + 8);
    *(int4*)(tk + 12) = *(const int4*)(tp + 12);
    int c = 0;
#pragma unroll
    for (int t = 0; t < BAG; t++) c += (tk[t] != PAD_IDX);
    float a[8];
#pragma unroll
    for (int j = 0; j < 8; j++) a[j] = 0.f;
    v8s v[16];
#pragma unroll
    for (int t = 0; t < 16; t++)
        v[t] = *(const v8s*)(table + (size_t)tk[t] * EMB + sl * 8);
#pragma unroll
    for (int t = 0; t < 16; t++) acc8(a, v[t]);
    float inv = 1.0f / (float)(c > 0 ? c : 1);
    uint4 o;
    o.x = f2bf(a[0] * inv) | ((unsigned)f2bf(a[1] * inv) << 16);
    o.y = f2bf(a[2] * inv) | ((unsigned)f2bf(a[3] * inv) << 16);
    o.z = f2bf(a[4] * inv) | ((unsigned)f2bf(a[5] * inv) << 16);
    o.w = f2bf(a[6] * inv) | ((unsigned)f2bf(a[7] * inv) << 16);
    *(uint4*)(x0 + (size_t)node * EMB + sl * 8) = o;
}

// ---------- neighbor mean aggregation (slot-CSR), 2 nodes per wave ----------
// Slot rows padded to a multiple of 8 with sentinel NN (x row NN is zero), so the
// gather loop is a single unconditional 8-stride loop. Two independent node chains
// per wave -> 4KB in flight; bounded by random-gather throughput (L2/L3-resident x).
// 6250 blocks -> ~32 waves/CU: this concurrency is why the standalone kernel beats
// tile-fused aggregation (round-9: fused at 8 waves/CU was 3x slower).
__global__ __launch_bounds__(256) void k_aggr(const unsigned short* __restrict__ x,
                                              const int* __restrict__ cnt,
                                              const unsigned short* __restrict__ slots,
                                              unsigned short* __restrict__ aggr) {
    int wv = threadIdx.x >> 6;
    int lane = threadIdx.x & 63;
    int n0 = (blockIdx.x * 4 + wv) * 2;  // exact: NN = 6250*8
    int n1 = n0 + 1;
    int g = lane >> 4, sl = lane & 15;
    int deg0 = cnt[n0], deg1 = cnt[n1];
    int m0 = deg0 > SLOTS ? SLOTS : deg0;
    int m1 = deg1 > SLOTS ? SLOTS : deg1;
    int m80 = (m0 + 7) & ~7;
    int m81 = (m1 + 7) & ~7;
    int idx0 = slots[(size_t)n0 * SLOTS + lane];
    int idx1 = slots[(size_t)n1 * SLOTS + lane];
    float a0[8], a1[8];
#pragma unroll
    for (int j = 0; j < 8; j++) {
        a0[j] = 0.f;
        a1[j] = 0.f;
    }
    int mm = m80 > m81 ? m80 : m81;
#pragma unroll 2
    for (int i = 0; i < mm; i += 8) {
        bool c0 = (i < m80), c1 = (i < m81);  // wave-uniform branches
        v8s w0, w1, w2, w3;
        if (c0) {
            int t00 = __shfl(idx0, i + g, 64);
            int t01 = __shfl(idx0, i + 4 + g, 64);
            w0 = *(const v8s*)(x + (size_t)t00 * HID + sl * 8);
            w1 = *(const v8s*)(x + (size_t)t01 * HID + sl * 8);
        }
        if (c1) {
            int t10 = __shfl(idx1, i + g, 64);
            int t11 = __shfl(idx1, i + 4 + g, 64);
            w2 = *(const v8s*)(x + (size_t)t10 * HID + sl * 8);
            w3 = *(const v8s*)(x + (size_t)t11 * HID + sl * 8);
        }
        if (c0) {
            acc8(a0, w0);
            acc8(a0, w1);
        }
        if (c1) {
            acc8(a1, w2);
            acc8(a1, w3);
        }
    }
#pragma unroll
    for (int j = 0; j < 8; j++) {
        a0[j] += __shfl_xor(a0[j], 16, 64);
        a0[j] += __shfl_xor(a0[j], 32, 64);
        a1[j] += __shfl_xor(a1[j], 16, 64);
        a1[j] += __shfl_xor(a1[j], 32, 64);
    }
    if (g == 0) {
        float inv = 1.0f / (float)(deg0 > 0 ? deg0 : 1);
        uint4 o;
        o.x = f2bf(a0[0] * inv) | ((unsigned)f2bf(a0[1] * inv) << 16);
        o.y = f2bf(a0[2] * inv) | ((unsigned)f2bf(a0[3] * inv) << 16);
        o.z = f2bf(a0[4] * inv) | ((unsigned)f2bf(a0[5] * inv) << 16);
        o.w = f2bf(a0[6] * inv) | ((unsigned)f2bf(a0[7] * inv) << 16);
        *(uint4*)(aggr + (size_t)n0 * HID + sl * 8) = o;
    } else if (g == 1) {
        float inv = 1.0f / (float)(deg1 > 0 ? deg1 : 1);
        uint4 o;
        o.x = f2bf(a1[0] * inv) | ((unsigned)f2bf(a1[1] * inv) << 16);
        o.y = f2bf(a1[2] * inv) | ((unsigned)f2bf(a1[3] * inv) << 16);
        o.z = f2bf(a1[4] * inv) | ((unsigned)f2bf(a1[5] * inv) << 16);
        o.w = f2bf(a1[6] * inv) | ((unsigned)f2bf(a1[7] * inv) << 16);
        *(uint4*)(aggr + (size_t)n1 * HID + sl * 8) = o;
    }
}

// ---------- shared MFMA K-loop for a 128-row tile (software-pipelined) ----------
// Next K-chunk's A/B staged global->regs DURING current chunk's MFMA (addresses
// are kc-invariant), so global latency hides under compute instead of sitting
// between the two barriers. ASTR=40 row stride kills the 8-way ds_read_b128
// bank conflict of the old 32-stride layout (lanes l16/l16+8 now 2-way = free).
__device__ __forceinline__ void sage_kloop(int row0, const unsigned short* __restrict__ xa,
                                           const unsigned short* __restrict__ xr,
                                           const unsigned short* __restrict__ wl,
                                           const unsigned short* __restrict__ wr,
                                           unsigned short* As, unsigned short* Bs,
                                           v4f acc[2][8]) {
    int tid = threadIdx.x;
    int wave = tid >> 6, lane = tid & 63;
    int q = lane >> 4, l16 = lane & 15;
    int r0 = tid >> 2, sg = tid & 3;       // it=0: rows 0..63
    int r1 = (tid + 256) >> 2;             // it=1: rows 64..127 (same sg)
    int gr0 = row0 + r0;
    if (gr0 > NN - 1) gr0 = NN - 1;
    int gr1 = row0 + r1;
    if (gr1 > NN - 1) gr1 = NN - 1;
    v8s ra0 = *(const v8s*)(xa + (size_t)gr0 * HID + sg * 8);
    v8s ra1 = *(const v8s*)(xa + (size_t)gr1 * HID + sg * 8);
    v8s rb0 = *(const v8s*)(wl + (size_t)r0 * HID + sg * 8);
    v8s rb1 = *(const v8s*)(wl + (size_t)r1 * HID + sg * 8);
    for (int kc = 0; kc < 8; kc++) {
        __syncthreads();  // prior kc's LDS reads complete (no-op at kc=0)
        *(v8s*)(As + r0 * ASTR + sg * 8) = ra0;
        *(v8s*)(As + r1 * ASTR + sg * 8) = ra1;
        *(v8s*)(Bs + r0 * ASTR + sg * 8) = rb0;
        *(v8s*)(Bs + r1 * ASTR + sg * 8) = rb1;
        __syncthreads();
        if (kc < 7) {  // prefetch next chunk; latency overlaps MFMA below
            int kn = kc + 1;
            const unsigned short* Ag = (kn < 4) ? xa : xr;
            const unsigned short* Bg = (kn < 4) ? wl : wr;
            int koff = (kn & 3) * 32;
            ra0 = *(const v8s*)(Ag + (size_t)gr0 * HID + koff + sg * 8);
            ra1 = *(const v8s*)(Ag + (size_t)gr1 * HID + koff + sg * 8);
            rb0 = *(const v8s*)(Bg + (size_t)r0 * HID + koff + sg * 8);
            rb1 = *(const v8s*)(Bg + (size_t)r1 * HID + koff + sg * 8);
        }
        v8s a0 = *(const v8s*)(As + (wave * 32 + l16) * ASTR + q * 8);
        v8s a1 = *(const v8s*)(As + (wave * 32 + 16 + l16) * ASTR + q * 8);
#pragma unroll
        for (int nt = 0; nt < 8; nt++) {
            v8s b = *(const v8s*)(Bs + (nt * 16 + l16) * ASTR + q * 8);
            acc[0][nt] = __builtin_amdgcn_mfma_f32_16x16x32_bf16(a0, b, acc[0][nt], 0, 0, 0);
            acc[1][nt] = __builtin_amdgcn_mfma_f32_16x16x32_bf16(a1, b, acc[1][nt], 0, 0, 0);
        }
    }
    __syncthreads();  // LDS reads done before caller reuses the tile
}

// ---------- SAGE layer 1: relu(aggr@wl^T + b + x@wr^T) -> global x1 ----------
__global__ __launch_bounds__(256) void k_sage(const unsigned short* __restrict__ xa,
                                              const unsigned short* __restrict__ xr,
                                              const unsigned short* __restrict__ wl,
                                              const unsigned short* __restrict__ wr,
                                              const float* __restrict__ bias,
                                              unsigned short* __restrict__ out) {
    __shared__ unsigned short As[128 * ASTR];
    __shared__ unsigned short Bs[128 * ASTR];
    int row0 = blockIdx.x * 128;
    v4f acc[2][8];
#pragma unroll
    for (int m = 0; m < 2; m++)
#pragma unroll
        for (int n = 0; n < 8; n++) acc[m][n] = (v4f){0.f, 0.f, 0.f, 0.f};
    sage_kloop(row0, xa, xr, wl, wr, As, Bs, acc);
    int tid = threadIdx.x;
    int wave = tid >> 6, lane = tid & 63;
    int q = lane >> 4, l16 = lane & 15;
#pragma unroll
    for (int nt = 0; nt < 8; nt++) {
        int col = nt * 16 + l16;
        float bv = bias[col];
#pragma unroll
        for (int mt = 0; mt < 2; mt++) {
#pragma unroll
            for (int r = 0; r < 4; r++) {
                int row = row0 + wave * 32 + mt * 16 + q * 4 + r;
                if (row < NN) {
                    float v = acc[mt][nt][r] + bv;
                    v = v > 0.f ? v : 0.f;
                    out[(size_t)row * HID + col] = f2bf(v);
                }
            }
        }
    }
}

// ---------- SAGE layer 2 fused with global mean pool ----------
__global__ __launch_bounds__(256) void k_sagepool(const unsigned short* __restrict__ xa,
                                                  const unsigned short* __restrict__ xr,
                                                  const unsigned short* __restrict__ wl,
                                                  const unsigned short* __restrict__ wr,
                                                  const float* __restrict__ bias,
                                                  const int* __restrict__ batch,
                                                  float* __restrict__ gsum,
                                                  float* __restrict__ gcnt) {
    __shared__ unsigned short smem[128 * 128];  // 32KB; first 20.5KB doubles as As|Bs
    unsigned short* As = smem;
    unsigned short* Bs = smem + 128 * ASTR;
    int row0 = blockIdx.x * 128;
    v4f acc[2][8];
#pragma unroll
    for (int m = 0; m < 2; m++)
#pragma unroll
        for (int n = 0; n < 8; n++) acc[m][n] = (v4f){0.f, 0.f, 0.f, 0.f};
    sage_kloop(row0, xa, xr, wl, wr, As, Bs, acc);
    // kloop ends with __syncthreads(); As/Bs dead -> overlay the x2 tile on smem
    int tid = threadIdx.x;
    int wave = tid >> 6, lane = tid & 63;
    int q = lane >> 4, l16 = lane & 15;
#pragma unroll
    for (int nt = 0; nt < 8; nt++) {
        int col = nt * 16 + l16;
        float bv = bias[col];
#pragma unroll
        for (int mt = 0; mt < 2; mt++) {
#pragma unroll
            for (int r = 0; r < 4; r++) {
                int rl = wave * 32 + mt * 16 + q * 4 + r;  // local row 0..127
                float v = acc[mt][nt][r] + bv;
                v = v > 0.f ? v : 0.f;
                smem[rl * 128 + col] = f2bf(v);
            }
        }
    }
    __syncthreads();
    // pool: thread col over this tile's rows (identical order to old k_pool chunk)
    if (tid < 128) {
        int col = tid;
        int end = NN - row0;
        if (end > 128) end = 128;
        int cur = batch[row0];
        float acc_p = 0.f;
        int c = 0;
        for (int i = 0; i < end; i++) {
            int b = batch[row0 + i];  // uniform across block
            if (b != cur) {
                atomicAdd(&gsum[cur * HID + col], acc_p);
                if (col == 0) atomicAdd(&gcnt[cur], (float)c);
                acc_p = 0.f;
                c = 0;
                cur = b;
            }
            acc_p += __uint_as_float(((unsigned)smem[i * 128 + col]) << 16);
            c++;
        }
        atomicAdd(&gsum[cur * HID + col], acc_p);
        if (col == 0) atomicAdd(&gcnt[cur], (float)c);
    }
}

// ---------- final classifier ----------
__global__ __launch_bounds__(128) void k_final(const float* __restrict__ gsum,
                                               const float* __restrict__ gcnt,
                                               const float* __restrict__ w_out,
                                               const float* __restrict__ b_out,
                                               float* __restrict__ out) {
    __shared__ float mean[HID];
    int g = blockIdx.x, tid = threadIdx.x;
    mean[tid] = gsum[g * HID + tid] / fmaxf(gcnt[g], 1.0f);
    __syncthreads();
    if (tid < NC) {
        float s = b_out[tid];
#pragma unroll 16
        for (int d = 0; d < HID; d++) s += mean[d] * w_out[tid * HID + d];
        out[g * NC + tid] = s;
    }
}

extern "C" void kernel_launch(void* const* d_in, const int* in_sizes, int n_in,
                              void* d_out, int out_size, void* d_ws, size_t ws_size,
                              hipStream_t stream) {
    const int* x_tokens = (const int*)d_in[0];
    const int* edge = (const int*)d_in[1];
    const int* batch = (const int*)d_in[2];
    const float* emb_table = (const float*)d_in[3];
    const float* w1l = (const float*)d_in[4];
    const float* b1 = (const float*)d_in[5];
    const float* w1r = (const float*)d_in[6];
    const float* w2l = (const float*)d_in[7];
    const float* b2 = (const float*)d_in[8];
    const float* w2r = (const float*)d_in[9];
    const float* w_out = (const float*)d_in[10];
    const float* b_out = (const float*)d_in[11];
    float* out = (float*)d_out;

    char* ws = (char*)d_ws;
    size_t off = 0;
    auto alloc = [&](size_t bytes) {
        void* p = ws + off;
        off += (bytes + 255) & ~(size_t)255;
        return p;
    };
    int* cnt = (int*)alloc(NN * 4);
    unsigned short* slots = (unsigned short*)alloc((size_t)NN * SLOTS * 2);  // 6.4 MB
    unsigned short* wbf = (unsigned short*)alloc(4 * HID * EMB * 2);
    float* gsum = (float*)alloc(NG * HID * 4);
    float* gcnt = (float*)alloc(NG * 4);
    unsigned short* x0 = (unsigned short*)alloc((size_t)(NN + 1) * EMB * 2);  // +zero row
    unsigned short* x1 = (unsigned short*)alloc((size_t)(NN + 1) * HID * 2);  // +zero row
    unsigned short* aggrb = (unsigned short*)alloc((size_t)NN * HID * 2);
    unsigned* queue = (unsigned*)alloc((size_t)RANGES * NCH1 * 64 * 4);  // 9.4 MB
    int* qcntG = (int*)alloc((size_t)RANGES * NCH1 * 4);                 // 146 KB
    unsigned short* table_bf = x1;  // x1 rows < VOCAB dead until sage1; reuse

    const int* srcp = edge;
    const int* dstp = edge + NE;

    k_conv<<<NCH1 + CONVB, 256, 0, stream>>>(srcp, dstp, queue, qcntG, emb_table,
                                             table_bf, w1l, w1r, w2l, w2r, wbf,
                                             gsum, gcnt, x0, x1);
    k_scatem<<<CSRB + EMVB, 256, 0, stream>>>(qcntG, queue, cnt, slots, x_tokens,
                                              table_bf, x0);
    k_aggr<<<NN / 8, 256, 0, stream>>>(x0, cnt, slots, aggrb);
    k_sage<<<NTILES, 256, 0, stream>>>(aggrb, x0, wbf, wbf + 16384, b1, x1);
    k_aggr<<<NN / 8, 256, 0, stream>>>(x1, cnt, slots, aggrb);
    k_sagepool<<<NTILES, 256, 0, stream>>>(aggrb, x1, wbf + 32768, wbf + 49152, b2,
                                           batch, gsum, gcnt);
    k_final<<<NG, 128, 0, stream>>>(gsum, gcnt, w_out, b_out, out);
}